// Round 10
// baseline (1806.133 us; speedup 1.0000x reference)
//
#include <hip/hip_runtime.h>

#define NB 256
#define NC 256
#define NL 25
#define ND 257
#define NOUT 32

// workspace layout (float offsets)
#define WS_WT 0         // 257*128 = 32896 floats (transposed g0)
#define WS_P  32896     // 256 * 3200 floats: per-b [u'(25x64) | v(25x64)], k-swizzled
#define WS_S  852096    // 256 * 64 floats: S[b][j] atomic accumulators

__device__ __forceinline__ float lrelu(float x) {
    return fmaxf(x, 0.0f) + 0.01f * fminf(x, 0.0f);
}

// Transpose g0_w (64 x 514) into wt[c][j], c in [0,257), j in [0,128):
//   j < 64 : A-part = g0_w[j][c] ; j >= 64 : B-part = g0_w[j-64][257+c]
__global__ void k_transpose(const float* __restrict__ g0, float* __restrict__ wt) {
    __shared__ float tile[64][65];
    const int cbase = blockIdx.x * 64;
    const int jh = blockIdx.y;
    const int tid = threadIdx.x;
    for (int i = tid; i < 64 * 64; i += 256) {
        int r = i >> 6, cc = i & 63, c = cbase + cc;
        float v = 0.0f;
        if (c < ND) v = g0[r * (2 * ND) + jh * ND + c];
        tile[r][cc] = v;
    }
    __syncthreads();
    for (int i = tid; i < 64 * 64; i += 256) {
        int cc = i >> 6, r = i & 63, c = cbase + cc;
        if (c < ND) wt[c * 128 + jh * 64 + r] = tile[r][cc];
    }
}

// Per-b projections: u'[p][k] = A.f_p + b0 ; v[p][k] = B.f_p  (k-swizzled store)
__global__ __launch_bounds__(512)
void k_prep(const float* __restrict__ x_img, const float* __restrict__ wt,
            const float* __restrict__ g0_b, float* __restrict__ wsP,
            float* __restrict__ wsS)
{
    __shared__ __align__(16) float xs[NC * NL];
    __shared__ __align__(16) float Pb[4 * 1600];
    __shared__ __align__(16) float b0s[64];

    const int tid = threadIdx.x;
    const int b = blockIdx.x;

    {   // stage x slice (coalesced float4)
        const float4* src = (const float4*)(x_img + (size_t)b * (NC * NL));
        float4* dst = (float4*)xs;
        for (int i = tid; i < 1600; i += 512) dst[i] = src[i];
    }
    if (tid < 64) b0s[tid] = g0_b[tid];
    if (tid >= 64 && tid < 128) wsS[b * 64 + (tid - 64)] = 0.0f;  // zero S[b][*]
    __syncthreads();

    // 512 threads = chalf(2) x pgrp(8: 3,3,3,3,3,3,3,4) x uv(2) x k4(16)
    {
        const int r     = tid & 255;
        const int chalf = tid >> 8;
        const int k4    = r & 15;
        const int uv    = (r >> 4) & 1;
        const int pgrp  = r >> 5;
        const int pstart = pgrp * 3;
        const bool p4   = (pgrp == 7);
        float4 a0 = {0.f,0.f,0.f,0.f}, a1 = a0, a2 = a0, a3 = a0;
        const float4* wp = ((const float4*)wt) + (uv * 16 + k4);  // row stride 32 float4
        const float* xrow = xs + pstart;
        const int c0   = chalf ? 128 : 0;
        const int cend = chalf ? 256 : 128;
        #pragma unroll 2
        for (int c = c0; c < cend; ++c) {
            const float4 w4 = wp[c * 32];
            const float f0 = xrow[c * 25 + 0];
            const float f1 = xrow[c * 25 + 1];
            const float f2 = xrow[c * 25 + 2];
            a0.x = fmaf(w4.x, f0, a0.x); a0.y = fmaf(w4.y, f0, a0.y);
            a0.z = fmaf(w4.z, f0, a0.z); a0.w = fmaf(w4.w, f0, a0.w);
            a1.x = fmaf(w4.x, f1, a1.x); a1.y = fmaf(w4.y, f1, a1.y);
            a1.z = fmaf(w4.z, f1, a1.z); a1.w = fmaf(w4.w, f1, a1.w);
            a2.x = fmaf(w4.x, f2, a2.x); a2.y = fmaf(w4.y, f2, a2.y);
            a2.z = fmaf(w4.z, f2, a2.z); a2.w = fmaf(w4.w, f2, a2.w);
            if (p4) {
                const float f3 = xrow[c * 25 + 3];
                a3.x = fmaf(w4.x, f3, a3.x); a3.y = fmaf(w4.y, f3, a3.y);
                a3.z = fmaf(w4.z, f3, a3.z); a3.w = fmaf(w4.w, f3, a3.w);
            }
        }
        if (chalf) {  // c = 256: coordinate feature f[p][256] = (float)p
            const float4 w4 = wp[256 * 32];
            const float f0 = (float)(pstart + 0);
            const float f1 = (float)(pstart + 1);
            const float f2 = (float)(pstart + 2);
            a0.x = fmaf(w4.x, f0, a0.x); a0.y = fmaf(w4.y, f0, a0.y);
            a0.z = fmaf(w4.z, f0, a0.z); a0.w = fmaf(w4.w, f0, a0.w);
            a1.x = fmaf(w4.x, f1, a1.x); a1.y = fmaf(w4.y, f1, a1.y);
            a1.z = fmaf(w4.z, f1, a1.z); a1.w = fmaf(w4.w, f1, a1.w);
            a2.x = fmaf(w4.x, f2, a2.x); a2.y = fmaf(w4.y, f2, a2.y);
            a2.z = fmaf(w4.z, f2, a2.z); a2.w = fmaf(w4.w, f2, a2.w);
            if (p4) {
                const float f3 = (float)(pstart + 3);
                a3.x = fmaf(w4.x, f3, a3.x); a3.y = fmaf(w4.y, f3, a3.y);
                a3.z = fmaf(w4.z, f3, a3.z); a3.w = fmaf(w4.w, f3, a3.w);
            }
        }
        float* dst = Pb + (chalf * 2 + uv) * 1600;
        *(float4*)&dst[(pstart + 0) * 64 + k4 * 4] = a0;
        *(float4*)&dst[(pstart + 1) * 64 + k4 * 4] = a1;
        *(float4*)&dst[(pstart + 2) * 64 + k4 * 4] = a2;
        if (p4) *(float4*)&dst[(pstart + 3) * 64 + k4 * 4] = a3;
    }
    __syncthreads();

    // merge chalf halves, fold bias into u', swizzle columns, write to ws
    for (int i = tid; i < 800; i += 512) {
        const int uv  = i >= 400;
        const int rem = i - uv * 400;
        const int p   = rem >> 4;
        const int k4  = rem & 15;
        const float4 pa = *(const float4*)&Pb[uv * 1600 + p * 64 + k4 * 4];
        const float4 pc = *(const float4*)&Pb[(2 + uv) * 1600 + p * 64 + k4 * 4];
        float4 o;
        o.x = pa.x + pc.x; o.y = pa.y + pc.y;
        o.z = pa.z + pc.z; o.w = pa.w + pc.w;
        if (!uv) {
            o.x += b0s[k4 * 4 + 0]; o.y += b0s[k4 * 4 + 1];
            o.z += b0s[k4 * 4 + 2]; o.w += b0s[k4 * 4 + 3];
        }
        *(float4*)&wsP[(size_t)b * 3200 + uv * 1600 + p * 64 + ((k4 ^ (p & 15)) << 2)] = o;
    }
}

// Pair kernel: 1280 blocks = 256 b x 5 splits of 125 pairs. 256 threads.
// Wave w: pair-group (w>>1), j-group (w&1)*32. Lane = 1 pair.
// h computed on the fly (no register array to demote); acc[32] RMW accumulators.
__global__ __launch_bounds__(256)
void k_pair(const float* __restrict__ wsP, const float* __restrict__ g1_w,
            const float* __restrict__ g1_b, float* __restrict__ wsS)
{
    __shared__ __align__(16) float uvl[3200];
    const int tid  = threadIdx.x;
    const int lane = tid & 63;
    const int wid  = tid >> 6;
    const int bs   = blockIdx.x;
    const int b    = bs / 5;
    const int split = bs - b * 5;

    {   // stage this b's u'|v (already swizzled) — 800 float4, coalesced
        const float4* src = (const float4*)(wsP + (size_t)b * 3200);
        float4* dst = (float4*)uvl;
        for (int i = tid; i < 800; i += 256) dst[i] = src[i];
    }
    __syncthreads();

    const int jb = (wid & 1) * 32;                 // wave's j-base (wave-uniform)
    const int lo = (wid >> 1) * 64 + lane;         // pair slot 0..127
    const bool ok = lo < 125;
    const int pp = split * 125 + (ok ? lo : 0);    // clamped index stays in-range
    const int l  = (pp * 5243) >> 17;              // pp / 25
    const int m  = pp - l * 25;
    const int ub = m * 64;          const int usw = m & 15;
    const int vb = 1600 + l * 64;   const int vsw = l & 15;
    const float* __restrict__ gbase = g1_w + (size_t)jb * 64;  // uniform

    float acc[32];
    #pragma unroll
    for (int q = 0; q < 32; ++q) acc[q] = 0.f;

    #pragma unroll
    for (int kc = 0; kc < 16; ++kc) {
        const float4 u4 = *(const float4*)&uvl[ub + ((kc ^ usw) << 2)];
        const float4 v4 = *(const float4*)&uvl[vb + ((kc ^ vsw) << 2)];
        float4 h;
        h.x = lrelu(u4.x + v4.x);
        h.y = lrelu(u4.y + v4.y);
        h.z = lrelu(u4.z + v4.z);
        h.w = lrelu(u4.w + v4.w);
        #pragma unroll
        for (int q = 0; q < 32; ++q) {
            const float4 g4 = *(const float4*)(gbase + q * 64 + kc * 4);  // s_load, imm offset
            acc[q] = fmaf(g4.x, h.x, acc[q]);
            acc[q] = fmaf(g4.y, h.y, acc[q]);
            acc[q] = fmaf(g4.z, h.z, acc[q]);
            acc[q] = fmaf(g4.w, h.w, acc[q]);
        }
    }

    // lrelu + mask, butterfly-reduce over 64 lanes, one atomic per j
    float vout = 0.f;
    #pragma unroll
    for (int q = 0; q < 32; ++q) {
        float s = ok ? lrelu(acc[q] + g1_b[jb + q]) : 0.f;
        s += __shfl_xor(s, 1, 64);
        s += __shfl_xor(s, 2, 64);
        s += __shfl_xor(s, 4, 64);
        s += __shfl_xor(s, 8, 64);
        s += __shfl_xor(s, 16, 64);
        s += __shfl_xor(s, 32, 64);
        vout = (lane == q) ? s : vout;
    }
    if (lane < 32) atomicAdd(&wsS[b * 64 + jb + lane], vout);
}

// Final 2-layer MLP per b
__global__ __launch_bounds__(64)
void k_post(const float* __restrict__ wsS, const float* __restrict__ post_w,
            const float* __restrict__ post_b, const float* __restrict__ out_w,
            const float* __restrict__ out_b, float* __restrict__ out)
{
    __shared__ float ss[64], zs[64];
    const int b = blockIdx.x, tid = threadIdx.x;
    ss[tid] = wsS[b * 64 + tid];
    __syncthreads();
    float a = post_b[tid];
    #pragma unroll 8
    for (int k = 0; k < 64; ++k) a = fmaf(post_w[tid * 64 + k], ss[k], a);
    zs[tid] = lrelu(a);
    __syncthreads();
    if (tid < NOUT) {
        float a2 = out_b[tid];
        #pragma unroll 8
        for (int k = 0; k < 64; ++k) a2 = fmaf(out_w[tid * 64 + k], zs[k], a2);
        out[b * NOUT + tid] = lrelu(a2);
    }
}

extern "C" void kernel_launch(void* const* d_in, const int* in_sizes, int n_in,
                              void* d_out, int out_size, void* d_ws, size_t ws_size,
                              hipStream_t stream) {
    const float* x_img  = (const float*)d_in[0];
    const float* g0_w   = (const float*)d_in[1];
    const float* g0_b   = (const float*)d_in[2];
    const float* g1_w   = (const float*)d_in[3];
    const float* g1_b   = (const float*)d_in[4];
    const float* post_w = (const float*)d_in[5];
    const float* post_b = (const float*)d_in[6];
    const float* out_w  = (const float*)d_in[7];
    const float* out_b  = (const float*)d_in[8];
    float* out = (float*)d_out;
    float* ws  = (float*)d_ws;   // 868,480 floats = 3.47 MB

    k_transpose<<<dim3(5, 2), 256, 0, stream>>>(g0_w, ws + WS_WT);
    k_prep<<<NB, 512, 0, stream>>>(x_img, ws + WS_WT, g0_b, ws + WS_P, ws + WS_S);
    k_pair<<<NB * 5, 256, 0, stream>>>(ws + WS_P, g1_w, g1_b, ws + WS_S);
    k_post<<<NB, 64, 0, stream>>>(ws + WS_S, post_w, post_b, out_w, out_b, out);
}

// Round 12
// 171.286 us; speedup vs baseline: 10.5445x; 10.5445x over previous
//
#include <hip/hip_runtime.h>

#define NB 256
#define NC 256
#define NL 25
#define ND 257
#define NOUT 32

__device__ __forceinline__ float lrelu(float x) {
    return fmaxf(x, 0.0f) + 0.01f * fminf(x, 0.0f);
}

// Transpose g0_w (64 x 514) into wt[c][j], c in [0,257), j in [0,128):
//   j < 64 : A-part = g0_w[j][c] ; j >= 64 : B-part = g0_w[j-64][257+c]
__global__ void k_transpose(const float* __restrict__ g0, float* __restrict__ wt) {
    __shared__ float tile[64][65];
    const int cbase = blockIdx.x * 64;
    const int jh = blockIdx.y;
    const int tid = threadIdx.x;
    for (int i = tid; i < 64 * 64; i += 256) {
        int r = i >> 6, cc = i & 63, c = cbase + cc;
        float v = 0.0f;
        if (c < ND) v = g0[r * (2 * ND) + jh * ND + c];
        tile[r][cc] = v;
    }
    __syncthreads();
    for (int i = tid; i < 64 * 64; i += 256) {
        int cc = i >> 6, r = i & 63, c = cbase + cc;
        if (c < ND) wt[c * 128 + jh * 64 + r] = tile[r][cc];
    }
}

__global__ __launch_bounds__(512, 4)   // cap VGPR at 128 -> 2 blocks/CU (LDS 51.5KB)
void k_main(const float* __restrict__ x_img,
            const float* __restrict__ wt,      // [257][128]
            const float* __restrict__ g0_b,
            const float* __restrict__ g1_w,
            const float* __restrict__ g1_b,
            const float* __restrict__ post_w,
            const float* __restrict__ post_b,
            const float* __restrict__ out_w,
            const float* __restrict__ out_b,
            float* __restrict__ out)
{
    // xs (phase 1) aliased by uvl+red+sf+zs (phase 2) — barrier-separated
    __shared__ __align__(16) float xsu[6400];
    __shared__ __align__(16) float Pb[6400];
    __shared__ __align__(16) float b0s[64];
    float* xs  = xsu;          // 6400, phase 1 only
    float* uvl = xsu;          // 3200: u'(25x64 swz) | v(25x64 swz)
    float* red = xsu + 3200;   // 64*5 partials
    float* zs  = xsu + 3520;   // 64
    float* sf  = xsu + 3584;   // 64

    const int tid  = threadIdx.x;
    const int b    = blockIdx.x;
    const int lane = tid & 63;
    const int wid  = tid >> 6;

    // ---- stage x slice (coalesced float4) ----
    {
        const float4* src = (const float4*)(x_img + (size_t)b * (NC * NL));
        float4* dst = (float4*)xs;
        for (int i = tid; i < 1600; i += 512) dst[i] = src[i];
    }
    if (tid < 64) b0s[tid] = g0_b[tid];
    __syncthreads();

    // ---- phase 1: partial projections into Pb[chalf*2+uv][p][k] ----
    // 512 threads = chalf(2) x pgrp(8: 3,3,3,3,3,3,3,4) x uv(2) x k4(16)
    {
        const int r     = tid & 255;
        const int chalf = tid >> 8;
        const int k4    = r & 15;
        const int uv    = (r >> 4) & 1;
        const int pgrp  = r >> 5;
        const int pstart = pgrp * 3;
        const bool p4   = (pgrp == 7);
        float4 a0 = {0.f,0.f,0.f,0.f}, a1 = a0, a2 = a0, a3 = a0;
        const float4* wp = ((const float4*)wt) + (uv * 16 + k4);  // row stride 32 float4
        const float* xrow = xs + pstart;
        const int c0   = chalf ? 128 : 0;
        const int cend = chalf ? 256 : 128;
        #pragma unroll 2
        for (int c = c0; c < cend; ++c) {
            const float4 w4 = wp[c * 32];
            const float f0 = xrow[c * 25 + 0];
            const float f1 = xrow[c * 25 + 1];
            const float f2 = xrow[c * 25 + 2];
            a0.x = fmaf(w4.x, f0, a0.x); a0.y = fmaf(w4.y, f0, a0.y);
            a0.z = fmaf(w4.z, f0, a0.z); a0.w = fmaf(w4.w, f0, a0.w);
            a1.x = fmaf(w4.x, f1, a1.x); a1.y = fmaf(w4.y, f1, a1.y);
            a1.z = fmaf(w4.z, f1, a1.z); a1.w = fmaf(w4.w, f1, a1.w);
            a2.x = fmaf(w4.x, f2, a2.x); a2.y = fmaf(w4.y, f2, a2.y);
            a2.z = fmaf(w4.z, f2, a2.z); a2.w = fmaf(w4.w, f2, a2.w);
            if (p4) {
                const float f3 = xrow[c * 25 + 3];
                a3.x = fmaf(w4.x, f3, a3.x); a3.y = fmaf(w4.y, f3, a3.y);
                a3.z = fmaf(w4.z, f3, a3.z); a3.w = fmaf(w4.w, f3, a3.w);
            }
        }
        if (chalf) {  // c = 256: coordinate feature f[p][256] = (float)p
            const float4 w4 = wp[256 * 32];
            const float f0 = (float)(pstart + 0);
            const float f1 = (float)(pstart + 1);
            const float f2 = (float)(pstart + 2);
            a0.x = fmaf(w4.x, f0, a0.x); a0.y = fmaf(w4.y, f0, a0.y);
            a0.z = fmaf(w4.z, f0, a0.z); a0.w = fmaf(w4.w, f0, a0.w);
            a1.x = fmaf(w4.x, f1, a1.x); a1.y = fmaf(w4.y, f1, a1.y);
            a1.z = fmaf(w4.z, f1, a1.z); a1.w = fmaf(w4.w, f1, a1.w);
            a2.x = fmaf(w4.x, f2, a2.x); a2.y = fmaf(w4.y, f2, a2.y);
            a2.z = fmaf(w4.z, f2, a2.z); a2.w = fmaf(w4.w, f2, a2.w);
            if (p4) {
                const float f3 = (float)(pstart + 3);
                a3.x = fmaf(w4.x, f3, a3.x); a3.y = fmaf(w4.y, f3, a3.y);
                a3.z = fmaf(w4.z, f3, a3.z); a3.w = fmaf(w4.w, f3, a3.w);
            }
        }
        float* dst = Pb + (chalf * 2 + uv) * 1600;
        *(float4*)&dst[(pstart + 0) * 64 + k4 * 4] = a0;
        *(float4*)&dst[(pstart + 1) * 64 + k4 * 4] = a1;
        *(float4*)&dst[(pstart + 2) * 64 + k4 * 4] = a2;
        if (p4) *(float4*)&dst[(pstart + 3) * 64 + k4 * 4] = a3;
    }
    __syncthreads();  // Pb ready; xs dead -> uvl region writable

    // ---- merge halves, fold bias into u', store k-swizzled u'|v in LDS ----
    for (int i = tid; i < 800; i += 512) {
        const int uv  = i >= 400;
        const int rem = i - uv * 400;
        const int p   = rem >> 4;
        const int k4  = rem & 15;
        const float4 pa = *(const float4*)&Pb[uv * 1600 + p * 64 + k4 * 4];
        const float4 pc = *(const float4*)&Pb[(2 + uv) * 1600 + p * 64 + k4 * 4];
        float4 o;
        o.x = pa.x + pc.x; o.y = pa.y + pc.y;
        o.z = pa.z + pc.z; o.w = pa.w + pc.w;
        if (!uv) {
            o.x += b0s[k4 * 4 + 0]; o.y += b0s[k4 * 4 + 1];
            o.z += b0s[k4 * 4 + 2]; o.w += b0s[k4 * 4 + 3];
        }
        *(float4*)&uvl[uv * 1600 + p * 64 + ((k4 ^ (p & 15)) << 2)] = o;
    }
    __syncthreads();

    // ---- phase 2: wave = (pair-group pg, j-half). h computed on the fly.
    // dot[32] and accS[32] are RMW accumulators (statically indexed -> VGPRs).
    // g1 rows via readfirstlane-uniform base -> s_load_dwordx4 (SGPR operand).
    const int pg = wid >> 1;
    const int jb = __builtin_amdgcn_readfirstlane((wid & 1) * 32);
    const float* __restrict__ gbase = g1_w + (size_t)jb * 64;

    float accS[32];
    #pragma unroll
    for (int q = 0; q < 32; ++q) accS[q] = 0.f;

    #pragma unroll 1
    for (int batch = pg; batch < 10; batch += 4) {
        const int pp0 = batch * 64 + lane;
        const bool ok = pp0 < 625;
        const int pp = ok ? pp0 : 624;
        const int l = (pp * 5243) >> 17;          // pp / 25
        const int m = pp - l * 25;
        const int ub = m * 64;          const int usw = m & 15;
        const int vb = 1600 + l * 64;   const int vsw = l & 15;

        float dot[32];
        #pragma unroll
        for (int q = 0; q < 32; ++q) dot[q] = 0.f;

        #pragma unroll 2
        for (int kc = 0; kc < 16; ++kc) {
            const float4 u4 = *(const float4*)&uvl[ub + ((kc ^ usw) << 2)];
            const float4 v4 = *(const float4*)&uvl[vb + ((kc ^ vsw) << 2)];
            float4 h;
            h.x = lrelu(u4.x + v4.x);
            h.y = lrelu(u4.y + v4.y);
            h.z = lrelu(u4.z + v4.z);
            h.w = lrelu(u4.w + v4.w);
            #pragma unroll
            for (int q = 0; q < 32; ++q) {
                const float4 g4 = *(const float4*)(gbase + q * 64 + kc * 4);  // uniform
                dot[q] = fmaf(g4.x, h.x, dot[q]);
                dot[q] = fmaf(g4.y, h.y, dot[q]);
                dot[q] = fmaf(g4.z, h.z, dot[q]);
                dot[q] = fmaf(g4.w, h.w, dot[q]);
            }
        }
        #pragma unroll
        for (int q = 0; q < 32; ++q) {
            const float t = lrelu(dot[q] + g1_b[jb + q]);
            accS[q] += ok ? t : 0.0f;
        }
    }

    // ---- butterfly-reduce each j over 64 lanes; write per-(j, pg) partial ----
    {
        float vout = 0.f;
        #pragma unroll
        for (int q = 0; q < 32; ++q) {
            float s = accS[q];
            s += __shfl_xor(s, 1, 64);
            s += __shfl_xor(s, 2, 64);
            s += __shfl_xor(s, 4, 64);
            s += __shfl_xor(s, 8, 64);
            s += __shfl_xor(s, 16, 64);
            s += __shfl_xor(s, 32, 64);
            vout = (lane == q) ? s : vout;
        }
        if (lane < 32) red[(jb + lane) * 5 + pg] = vout;
    }
    __syncthreads();

    // ---- final sum + 2-layer MLP (wave 0 only; no further barriers needed) ----
    if (tid < 64) {
        const float* rp = red + tid * 5;
        sf[tid] = ((rp[0] + rp[1]) + (rp[2] + rp[3]));
        float a = post_b[tid];
        #pragma unroll 8
        for (int k = 0; k < 64; ++k) a = fmaf(post_w[tid * 64 + k], sf[k], a);
        zs[tid] = lrelu(a);
        if (tid < NOUT) {
            float a2 = out_b[tid];
            #pragma unroll 8
            for (int k = 0; k < 64; ++k) a2 = fmaf(out_w[tid * 64 + k], zs[k], a2);
            out[b * NOUT + tid] = lrelu(a2);
        }
    }
}

extern "C" void kernel_launch(void* const* d_in, const int* in_sizes, int n_in,
                              void* d_out, int out_size, void* d_ws, size_t ws_size,
                              hipStream_t stream) {
    const float* x_img  = (const float*)d_in[0];
    const float* g0_w   = (const float*)d_in[1];
    const float* g0_b   = (const float*)d_in[2];
    const float* g1_w   = (const float*)d_in[3];
    const float* g1_b   = (const float*)d_in[4];
    const float* post_w = (const float*)d_in[5];
    const float* post_b = (const float*)d_in[6];
    const float* out_w  = (const float*)d_in[7];
    const float* out_b  = (const float*)d_in[8];
    float* out = (float*)d_out;
    float* wt  = (float*)d_ws;  // 257*128 fp32

    k_transpose<<<dim3(5, 2), 256, 0, stream>>>(g0_w, wt);
    k_main<<<NB, 512, 0, stream>>>(x_img, wt, g0_b, g1_w, g1_b,
                                   post_w, post_b, out_w, out_b, out);
}

// Round 13
// 170.813 us; speedup vs baseline: 10.5738x; 1.0028x over previous
//
#include <hip/hip_runtime.h>

#define NB 256
#define NC 256
#define NL 25
#define ND 257
#define NOUT 32

// workspace layout (float offsets)
#define WS_WT 0        // 257*128 floats (transposed g0)
#define WS_S  32896    // 256 * 3 * 64 floats: per-(b, h) S partials

__device__ __forceinline__ float lrelu(float x) {
    return fmaxf(x, 0.01f * x);   // exact leaky-relu, 2 ops
}

// Transpose g0_w (64 x 514) into wt[c][j], c in [0,257), j in [0,128):
//   j < 64 : A-part = g0_w[j][c] ; j >= 64 : B-part = g0_w[j-64][257+c]
__global__ void k_transpose(const float* __restrict__ g0, float* __restrict__ wt) {
    __shared__ float tile[64][65];
    const int cbase = blockIdx.x * 64;
    const int jh = blockIdx.y;
    const int tid = threadIdx.x;
    for (int i = tid; i < 64 * 64; i += 256) {
        int r = i >> 6, cc = i & 63, c = cbase + cc;
        float v = 0.0f;
        if (c < ND) v = g0[r * (2 * ND) + jh * ND + c];
        tile[r][cc] = v;
    }
    __syncthreads();
    for (int i = tid; i < 64 * 64; i += 256) {
        int cc = i >> 6, r = i & 63, c = cbase + cc;
        if (c < ND) wt[c * 128 + jh * 64 + r] = tile[r][cc];
    }
}

// 768 blocks = 3 per b (3 blocks/CU: LDS 51.5KB*3 = 155KB <= 160KB).
__global__ __launch_bounds__(512, 4)
void k_main(const float* __restrict__ x_img,
            const float* __restrict__ wt,      // [257][128]
            const float* __restrict__ g0_b,
            const float* __restrict__ g1_w,
            const float* __restrict__ g1_b,
            float* __restrict__ wsS)
{
    __shared__ __align__(16) float xsu[6400];
    __shared__ __align__(16) float Pb[6400];
    __shared__ __align__(16) float b0s[64];
    float* xs  = xsu;          // 6400, phase 1 only
    float* uvl = xsu;          // 3200: u'(25x64 swz) | v(25x64 swz)
    float* red = xsu + 3200;   // 64*5 partials

    const int tid  = threadIdx.x;
    const unsigned bid = blockIdx.x;
    const int b    = (int)(bid / 3u);
    const int h    = (int)(bid - 3u * b);
    const int lane = tid & 63;
    const int wid  = tid >> 6;

    // ---- stage x slice (coalesced float4) ----
    {
        const float4* src = (const float4*)(x_img + (size_t)b * (NC * NL));
        float4* dst = (float4*)xs;
        for (int i = tid; i < 1600; i += 512) dst[i] = src[i];
    }
    if (tid < 64) b0s[tid] = g0_b[tid];
    __syncthreads();

    // ---- phase 1: partial projections into Pb[chalf*2+uv][p][k] ----
    // 512 threads = chalf(2) x pgrp(8: 3,3,3,3,3,3,3,4) x uv(2) x k4(16)
    {
        const int r     = tid & 255;
        const int chalf = tid >> 8;
        const int k4    = r & 15;
        const int uv    = (r >> 4) & 1;
        const int pgrp  = r >> 5;
        const int pstart = pgrp * 3;
        const bool p4   = (pgrp == 7);
        float4 a0 = {0.f,0.f,0.f,0.f}, a1 = a0, a2 = a0, a3 = a0;
        const float4* wp = ((const float4*)wt) + (uv * 16 + k4);  // row stride 32 float4
        const float* xrow = xs + pstart;
        const int c0   = chalf ? 128 : 0;
        const int cend = chalf ? 256 : 128;
        #pragma unroll 2
        for (int c = c0; c < cend; ++c) {
            const float4 w4 = wp[c * 32];
            const float f0 = xrow[c * 25 + 0];
            const float f1 = xrow[c * 25 + 1];
            const float f2 = xrow[c * 25 + 2];
            a0.x = fmaf(w4.x, f0, a0.x); a0.y = fmaf(w4.y, f0, a0.y);
            a0.z = fmaf(w4.z, f0, a0.z); a0.w = fmaf(w4.w, f0, a0.w);
            a1.x = fmaf(w4.x, f1, a1.x); a1.y = fmaf(w4.y, f1, a1.y);
            a1.z = fmaf(w4.z, f1, a1.z); a1.w = fmaf(w4.w, f1, a1.w);
            a2.x = fmaf(w4.x, f2, a2.x); a2.y = fmaf(w4.y, f2, a2.y);
            a2.z = fmaf(w4.z, f2, a2.z); a2.w = fmaf(w4.w, f2, a2.w);
            if (p4) {
                const float f3 = xrow[c * 25 + 3];
                a3.x = fmaf(w4.x, f3, a3.x); a3.y = fmaf(w4.y, f3, a3.y);
                a3.z = fmaf(w4.z, f3, a3.z); a3.w = fmaf(w4.w, f3, a3.w);
            }
        }
        if (chalf) {  // c = 256: coordinate feature f[p][256] = (float)p
            const float4 w4 = wp[256 * 32];
            const float f0 = (float)(pstart + 0);
            const float f1 = (float)(pstart + 1);
            const float f2 = (float)(pstart + 2);
            a0.x = fmaf(w4.x, f0, a0.x); a0.y = fmaf(w4.y, f0, a0.y);
            a0.z = fmaf(w4.z, f0, a0.z); a0.w = fmaf(w4.w, f0, a0.w);
            a1.x = fmaf(w4.x, f1, a1.x); a1.y = fmaf(w4.y, f1, a1.y);
            a1.z = fmaf(w4.z, f1, a1.z); a1.w = fmaf(w4.w, f1, a1.w);
            a2.x = fmaf(w4.x, f2, a2.x); a2.y = fmaf(w4.y, f2, a2.y);
            a2.z = fmaf(w4.z, f2, a2.z); a2.w = fmaf(w4.w, f2, a2.w);
            if (p4) {
                const float f3 = (float)(pstart + 3);
                a3.x = fmaf(w4.x, f3, a3.x); a3.y = fmaf(w4.y, f3, a3.y);
                a3.z = fmaf(w4.z, f3, a3.z); a3.w = fmaf(w4.w, f3, a3.w);
            }
        }
        float* dst = Pb + (chalf * 2 + uv) * 1600;
        *(float4*)&dst[(pstart + 0) * 64 + k4 * 4] = a0;
        *(float4*)&dst[(pstart + 1) * 64 + k4 * 4] = a1;
        *(float4*)&dst[(pstart + 2) * 64 + k4 * 4] = a2;
        if (p4) *(float4*)&dst[(pstart + 3) * 64 + k4 * 4] = a3;
    }
    __syncthreads();  // Pb ready; xs dead -> uvl region writable

    // ---- merge halves, fold bias into u', store k-swizzled u'|v in LDS ----
    for (int i = tid; i < 800; i += 512) {
        const int uv  = i >= 400;
        const int rem = i - uv * 400;
        const int p   = rem >> 4;
        const int k4  = rem & 15;
        const float4 pa = *(const float4*)&Pb[uv * 1600 + p * 64 + k4 * 4];
        const float4 pc = *(const float4*)&Pb[(2 + uv) * 1600 + p * 64 + k4 * 4];
        float4 o;
        o.x = pa.x + pc.x; o.y = pa.y + pc.y;
        o.z = pa.z + pc.z; o.w = pa.w + pc.w;
        if (!uv) {
            o.x += b0s[k4 * 4 + 0]; o.y += b0s[k4 * 4 + 1];
            o.z += b0s[k4 * 4 + 2]; o.w += b0s[k4 * 4 + 3];
        }
        *(float4*)&uvl[uv * 1600 + p * 64 + ((k4 ^ (p & 15)) << 2)] = o;
    }
    __syncthreads();

    // ---- phase 2: this block covers batches [start, start+count) of 10.
    // h0:{0..3} h1:{4..6} h2:{7..9}. Wave = (pg = wid>>1, jhalf = wid&1);
    // wave pg takes batch start+pg when pg < count, else idle (writes zeros).
    const int start = (h == 0) ? 0 : (3 * h + 1);
    const int count = (h == 0) ? 4 : 3;
    const int pg = wid >> 1;
    const int jb = __builtin_amdgcn_readfirstlane((wid & 1) * 32);
    const float* __restrict__ gbase = g1_w + (size_t)jb * 64;

    float accS[32];
    #pragma unroll
    for (int q = 0; q < 32; ++q) accS[q] = 0.f;

    if (pg < count) {
        const int batch = start + pg;
        const int pp0 = batch * 64 + lane;
        const bool ok = pp0 < 625;
        const int pp = ok ? pp0 : 624;
        const int l = (pp * 5243) >> 17;          // pp / 25
        const int m = pp - l * 25;
        const int ub = m * 64;          const int usw = m & 15;
        const int vb = 1600 + l * 64;   const int vsw = l & 15;

        float dot[32];
        #pragma unroll
        for (int q = 0; q < 32; ++q) dot[q] = 0.f;

        #pragma unroll 2
        for (int kc = 0; kc < 16; ++kc) {
            const float4 u4 = *(const float4*)&uvl[ub + ((kc ^ usw) << 2)];
            const float4 v4 = *(const float4*)&uvl[vb + ((kc ^ vsw) << 2)];
            float4 hh;
            hh.x = lrelu(u4.x + v4.x);
            hh.y = lrelu(u4.y + v4.y);
            hh.z = lrelu(u4.z + v4.z);
            hh.w = lrelu(u4.w + v4.w);
            #pragma unroll
            for (int q = 0; q < 32; ++q) {
                const float4 g4 = *(const float4*)(gbase + q * 64 + kc * 4);  // uniform
                dot[q] = fmaf(g4.x, hh.x, dot[q]);
                dot[q] = fmaf(g4.y, hh.y, dot[q]);
                dot[q] = fmaf(g4.z, hh.z, dot[q]);
                dot[q] = fmaf(g4.w, hh.w, dot[q]);
            }
        }
        #pragma unroll
        for (int q = 0; q < 32; ++q) {
            const float t = lrelu(dot[q] + g1_b[jb + q]);
            accS[q] += ok ? t : 0.0f;
        }
    }

    // ---- butterfly-reduce each j over 64 lanes; write per-(j, pg) partial ----
    {
        float vout = 0.f;
        #pragma unroll
        for (int q = 0; q < 32; ++q) {
            float s = accS[q];
            s += __shfl_xor(s, 1, 64);
            s += __shfl_xor(s, 2, 64);
            s += __shfl_xor(s, 4, 64);
            s += __shfl_xor(s, 8, 64);
            s += __shfl_xor(s, 16, 64);
            s += __shfl_xor(s, 32, 64);
            vout = (lane == q) ? s : vout;
        }
        if (lane < 32) red[(jb + lane) * 5 + pg] = vout;
    }
    __syncthreads();

    // ---- sum 4 pg-partials, write this block's S slice to workspace ----
    if (tid < 64) {
        const float* rp = red + tid * 5;
        wsS[(size_t)b * 192 + h * 64 + tid] = (rp[0] + rp[1]) + (rp[2] + rp[3]);
    }
}

// Final: sum 3 block partials + 2-layer MLP per b
__global__ __launch_bounds__(64)
void k_post(const float* __restrict__ wsS, const float* __restrict__ post_w,
            const float* __restrict__ post_b, const float* __restrict__ out_w,
            const float* __restrict__ out_b, float* __restrict__ out)
{
    __shared__ float ss[64], zs[64];
    const int b = blockIdx.x, tid = threadIdx.x;
    const float* sp = wsS + (size_t)b * 192;
    ss[tid] = sp[tid] + sp[64 + tid] + sp[128 + tid];
    __syncthreads();
    float a = post_b[tid];
    #pragma unroll 8
    for (int k = 0; k < 64; ++k) a = fmaf(post_w[tid * 64 + k], ss[k], a);
    zs[tid] = lrelu(a);
    __syncthreads();
    if (tid < NOUT) {
        float a2 = out_b[tid];
        #pragma unroll 8
        for (int k = 0; k < 64; ++k) a2 = fmaf(out_w[tid * 64 + k], zs[k], a2);
        out[b * NOUT + tid] = lrelu(a2);
    }
}

extern "C" void kernel_launch(void* const* d_in, const int* in_sizes, int n_in,
                              void* d_out, int out_size, void* d_ws, size_t ws_size,
                              hipStream_t stream) {
    const float* x_img  = (const float*)d_in[0];
    const float* g0_w   = (const float*)d_in[1];
    const float* g0_b   = (const float*)d_in[2];
    const float* g1_w   = (const float*)d_in[3];
    const float* g1_b   = (const float*)d_in[4];
    const float* post_w = (const float*)d_in[5];
    const float* post_b = (const float*)d_in[6];
    const float* out_w  = (const float*)d_in[7];
    const float* out_b  = (const float*)d_in[8];
    float* out = (float*)d_out;
    float* ws  = (float*)d_ws;

    k_transpose<<<dim3(5, 2), 256, 0, stream>>>(g0_w, ws + WS_WT);
    k_main<<<NB * 3, 512, 0, stream>>>(x_img, ws + WS_WT, g0_b, g1_w, g1_b, ws + WS_S);
    k_post<<<NB, 64, 0, stream>>>(ws + WS_S, post_w, post_b, out_w, out_b, out);
}